// Round 8
// baseline (173.206 us; speedup 1.0000x reference)
//
#include <hip/hip_runtime.h>
#include <stdint.h>

// Problem constants (from reference)
#define BATCH   8192
#define IN_DIM  256
#define OUT_DIM 64
#define NROW    68      // 67 spline rows + 1 silu row per d
#define N_SPLIT 16      // d-splits
#define D_SLICE 16      // d's per block (256/N_SPLIT)
#define N_STAGE 16      // 1 d per stage (R8: was 2 d x 8 stages)
#define M_BLK   256     // batch rows per block
#define NM      32      // 8192/M_BLK  (staging total ~ NM: keep at 32, R7 lesson)

typedef unsigned int u32;
typedef float f32x4 __attribute__((ext_vector_type(4)));
typedef u32   u32x2 __attribute__((ext_vector_type(2)));
typedef __bf16 bf16x2 __attribute__((ext_vector_type(2)));

#if defined(__has_builtin)
#  if __has_builtin(__builtin_amdgcn_fdot2_f32_bf16)
#    define HAVE_DOT2 1
#  endif
#endif
#ifndef HAVE_DOT2
#  define HAVE_DOT2 0
#endif

__device__ __forceinline__ u32 f2bf(float f) {              // f32 -> bf16 (RNE)
    u32 u = __float_as_uint(f);
    u += 0x7FFFu + ((u >> 16) & 1u);
    return u >> 16;
}
__device__ __forceinline__ float bflo(u32 u) { return __uint_as_float(u << 16); }
__device__ __forceinline__ float bfhi(u32 u) { return __uint_as_float(u & 0xFFFF0000u); }

// {lo, hi} f32 pair -> packed bf16x2 dword (HW v_cvt_pk_bf16_f32 via casts)
__device__ __forceinline__ u32 pkbf(float lo, float hi) {
    bf16x2 v = { (__bf16)lo, (__bf16)hi };
    u32 u;
    __builtin_memcpy(&u, &v, 4);
    return u;
}

// a, b are bf16x2 packed in u32 (element0 = low 16 bits): a0*b0 + a1*b1 + c
__device__ __forceinline__ float dot2bf(u32 a, u32 b, float c) {
#if HAVE_DOT2
    bf16x2 av, bv;
    __builtin_memcpy(&av, &a, 4);
    __builtin_memcpy(&bv, &b, 4);
    return __builtin_amdgcn_fdot2_f32_bf16(av, bv, c, false);
#else
    return fmaf(bflo(a), bflo(b), fmaf(bfhi(a), bfhi(b), c));
#endif
}

// knot t[i], i in [0,70]: 3 clamped zeros, linspace(0,1,65), 3 clamped ones.
__device__ __forceinline__ float knotf(int i) {
    return fminf(1.f, fmaxf(0.f, (float)(i - 3) * 0.015625f));
}

// Windowed Cox-de Boor (degree 3). Record: {c0|c1, c2|c3 (bf16x2), silu f32, s}
__device__ __forceinline__ void make_record(float x, u32 rec[4]) {
    int s = (int)floorf(x * 64.f);
    s = max(0, min(63, s));
    const int m = s + 3;
    float N0 = 1.f, N1, N2, N3;
    const float l1 = x - knotf(m);
    const float r1 = knotf(m + 1) - x;
    {
        float tmp = N0 / (r1 + l1);
        N0 = r1 * tmp;
        N1 = l1 * tmp;
    }
    const float l2 = x - knotf(m - 1);
    const float r2 = knotf(m + 2) - x;
    {
        float tmp = N0 / (r1 + l2);
        N0 = r1 * tmp;
        float saved = l2 * tmp;
        tmp = N1 / (r2 + l1);
        N1 = saved + r2 * tmp;
        N2 = l1 * tmp;
    }
    const float l3 = x - knotf(m - 2);
    const float r3 = knotf(m + 3) - x;
    {
        float tmp = N0 / (r1 + l3);
        N0 = r1 * tmp;
        float saved = l3 * tmp;
        tmp = N1 / (r2 + l2);
        N1 = saved + r2 * tmp;
        saved = l2 * tmp;
        tmp = N2 / (r3 + l1);
        N2 = saved + r3 * tmp;
        N3 = l1 * tmp;
    }
    const float silu = x / (1.f + __expf(-x));
    rec[0] = f2bf(N0) | (f2bf(N1) << 16);
    rec[1] = f2bf(N2) | (f2bf(N3) << 16);
    rec[2] = __float_as_uint(silu);
    rec[3] = (u32)s;
}

// LDS: two stage-buffers (double-buffered, 1 d each), 21248 B per buffer:
//   [0, 16896):        pair table: 66 pair-rows x 64 bf16x2, row stride 256 B,
//                      LINEAR (octet gather = one contiguous 128-B stripe)
//   [16896, 17152):    silu row (w row 67) as f32[64]
//   [17152, 21248):    coeff records [256 r] x 16 B
// Total 42496 B (same as R6).
#define TAB_OFF    0
#define SILU_OFF   16896
#define REC_OFF    17152
#define BUF_STRIDE 21248
#define LDS_U4     2656

__global__ __launch_bounds__(512, 4)   // cap 128 VGPR: guarantees 2 blocks/CU
void kan_main(const float* __restrict__ X, const float* __restrict__ W,
              void* __restrict__ outbuf, int useAtomic) {
    __shared__ uint4 smem4[LDS_U4];
    char* sm = (char*)smem4;

    const int mb  = blockIdx.x;          // 0..31
    const int sp  = blockIdx.y;          // 0..15
    const int tid = threadIdx.x;
    const int r0  = mb * M_BLK;
    const int d0  = sp * D_SLICE;

    const int lane = tid & 63;
    const int wv   = tid >> 6;           // wave 0..7
    const int sub  = lane & 7;           // output-chunk selector
    const int g    = lane >> 3;          // row-in-round 0..7
    const int rb   = wv * 32;            // wave's local row base

    // staging entry decomposition (1056 entries = 512 + 512 + 32 tail)
    const int c16 = tid & 15;            // 16-B chunk in pair-row
    const int e0r = tid >> 4;            //  0..31
    const int e1r = e0r + 32;            // 32..63
    const int e2r = e0r + 64;            // 64..65 (tid < 32 only)

    // prefetch registers (T14 issue-early / write-late)
    float4 va0, vb0, va1, vb1, va2, vb2;
    float xreg = 0.f, sreg = 0.f;

#define LOAD_REGS(DS) do {                                                     \
        const float* wb_ = W + (size_t)(DS) * (NROW * OUT_DIM);                \
        const float* p0_ = wb_ + e0r * OUT_DIM + c16 * 4;                      \
        va0 = *(const float4*)p0_;  vb0 = *(const float4*)(p0_ + OUT_DIM);     \
        const float* p1_ = wb_ + e1r * OUT_DIM + c16 * 4;                      \
        va1 = *(const float4*)p1_;  vb1 = *(const float4*)(p1_ + OUT_DIM);     \
        if (tid < 32) {                                                        \
            const float* p2_ = wb_ + e2r * OUT_DIM + c16 * 4;                  \
            va2 = *(const float4*)p2_;  vb2 = *(const float4*)(p2_ + OUT_DIM); \
        }                                                                      \
        if (tid >= 448) sreg = wb_[67 * OUT_DIM + (tid - 448)];                \
        if (tid < 256)  xreg = X[(size_t)(r0 + tid) * IN_DIM + (DS)];          \
    } while (0)

#define WRITE_STAGE(BN) do {                                                   \
        char* b_ = (BN);                                                       \
        *(uint4*)(b_ + TAB_OFF + e0r * 256 + c16 * 16) =                       \
            make_uint4(pkbf(va0.x, vb0.x), pkbf(va0.y, vb0.y),                 \
                       pkbf(va0.z, vb0.z), pkbf(va0.w, vb0.w));                \
        *(uint4*)(b_ + TAB_OFF + e1r * 256 + c16 * 16) =                       \
            make_uint4(pkbf(va1.x, vb1.x), pkbf(va1.y, vb1.y),                 \
                       pkbf(va1.z, vb1.z), pkbf(va1.w, vb1.w));                \
        if (tid < 32)                                                          \
            *(uint4*)(b_ + TAB_OFF + e2r * 256 + c16 * 16) =                   \
                make_uint4(pkbf(va2.x, vb2.x), pkbf(va2.y, vb2.y),             \
                           pkbf(va2.z, vb2.z), pkbf(va2.w, vb2.w));            \
        if (tid >= 448) *(float*)(b_ + SILU_OFF + (tid - 448) * 4) = sreg;     \
        if (tid < 256) {                                                       \
            u32 rec_[4];                                                       \
            make_record(xreg, rec_);                                           \
            *(uint4*)(b_ + REC_OFF + (tid << 4)) =                             \
                make_uint4(rec_[0], rec_[1], rec_[2], rec_[3]);                \
        }                                                                      \
    } while (0)

    float acc[4][8];
#pragma unroll
    for (int t = 0; t < 4; ++t)
#pragma unroll
        for (int k = 0; k < 8; ++k) acc[t][k] = 0.f;

    // ---- prologue: fill buffer 0, prefetch stage 1 ----
    LOAD_REGS(d0);
    WRITE_STAGE(sm);
    __syncthreads();
    LOAD_REGS(d0 + 1);

    for (int st = 0; st < N_STAGE; ++st) {
        char* bc = sm + (st & 1) * BUF_STRIDE;
        char* bn = sm + ((st & 1) ^ 1) * BUF_STRIDE;

        // ---- compute from bc (gather + dot2, 32 rows/wave) ----
        const f32x4 w67a = *(const f32x4*)(bc + SILU_OFF + sub * 16);
        const f32x4 w67b = *(const f32x4*)(bc + SILU_OFF + 128 + sub * 16);
#pragma unroll
        for (int t = 0; t < 4; ++t) {
            const uint4 rec = *(const uint4*)(bc + REC_OFF + ((rb + t * 8 + g) << 4));
            const u32 c01 = rec.x, c23 = rec.y;
            const float silu = __uint_as_float(rec.z);
            const int s = (int)rec.w;
            const char* r1 = bc + TAB_OFF + s * 256 + sub * 16;        // pair-row s
            const char* r2 = bc + TAB_OFF + (s + 2) * 256 + sub * 16;  // pair-row s+2
            const uint4 p1  = *(const uint4*)(r1);          // outputs sub*4..+3
            const uint4 p1b = *(const uint4*)(r1 + 128);    // outputs 32+sub*4..+3
            const uint4 p2  = *(const uint4*)(r2);
            const uint4 p2b = *(const uint4*)(r2 + 128);
            acc[t][0] = dot2bf(c23, p2.x,  dot2bf(c01, p1.x,  acc[t][0]));
            acc[t][1] = dot2bf(c23, p2.y,  dot2bf(c01, p1.y,  acc[t][1]));
            acc[t][2] = dot2bf(c23, p2.z,  dot2bf(c01, p1.z,  acc[t][2]));
            acc[t][3] = dot2bf(c23, p2.w,  dot2bf(c01, p1.w,  acc[t][3]));
            acc[t][4] = dot2bf(c23, p2b.x, dot2bf(c01, p1b.x, acc[t][4]));
            acc[t][5] = dot2bf(c23, p2b.y, dot2bf(c01, p1b.y, acc[t][5]));
            acc[t][6] = dot2bf(c23, p2b.z, dot2bf(c01, p1b.z, acc[t][6]));
            acc[t][7] = dot2bf(c23, p2b.w, dot2bf(c01, p1b.w, acc[t][7]));
            acc[t][0] = fmaf(silu, w67a.x, acc[t][0]);
            acc[t][1] = fmaf(silu, w67a.y, acc[t][1]);
            acc[t][2] = fmaf(silu, w67a.z, acc[t][2]);
            acc[t][3] = fmaf(silu, w67a.w, acc[t][3]);
            acc[t][4] = fmaf(silu, w67b.x, acc[t][4]);
            acc[t][5] = fmaf(silu, w67b.y, acc[t][5]);
            acc[t][6] = fmaf(silu, w67b.z, acc[t][6]);
            acc[t][7] = fmaf(silu, w67b.w, acc[t][7]);
        }

        // ---- write next stage (prefetched regs), single barrier, prefetch ----
        if (st < N_STAGE - 1) {
            WRITE_STAGE(bn);
            __syncthreads();
            if (st < N_STAGE - 2) LOAD_REGS(d0 + st + 2);
        }
    }

    // ---- emit partials as bf16 planes (streamed once, read once) ----
    if (!useAtomic) {
        char* wsp = (char*)outbuf + (size_t)sp * (BATCH * OUT_DIM * 2);
#pragma unroll
        for (int t = 0; t < 4; ++t) {
            const int R = r0 + rb + t * 8 + g;
            u32x2 lo = { pkbf(acc[t][0], acc[t][1]), pkbf(acc[t][2], acc[t][3]) };
            u32x2 hi = { pkbf(acc[t][4], acc[t][5]), pkbf(acc[t][6], acc[t][7]) };
            __builtin_nontemporal_store(lo, (u32x2*)(wsp + (size_t)R * 128 + sub * 8));
            __builtin_nontemporal_store(hi, (u32x2*)(wsp + (size_t)R * 128 + 64 + sub * 8));
        }
    } else {
        float* out = (float*)outbuf;
#pragma unroll
        for (int t = 0; t < 4; ++t) {
            const int R = r0 + rb + t * 8 + g;
#pragma unroll
            for (int k = 0; k < 4; ++k) {
                atomicAdd(out + (size_t)R * 64 + sub * 4 + k, acc[t][k]);
                atomicAdd(out + (size_t)R * 64 + 32 + sub * 4 + k, acc[t][k + 4]);
            }
        }
    }
#undef LOAD_REGS
#undef WRITE_STAGE
}

__global__ __launch_bounds__(256)
void kan_reduce(const u32* __restrict__ ws, float* __restrict__ out) {
    const int i = blockIdx.x * 256 + threadIdx.x;   // u32x2 index (4 bf16), 131072
    const u32x2* w2 = (const u32x2*)ws;
    float a0 = 0.f, a1 = 0.f, a2 = 0.f, a3 = 0.f;
#pragma unroll
    for (int s = 0; s < N_SPLIT; ++s) {
        u32x2 v = __builtin_nontemporal_load(
            &w2[(size_t)s * (BATCH * OUT_DIM / 4) + i]);
        a0 += bflo(v.x); a1 += bfhi(v.x);
        a2 += bflo(v.y); a3 += bfhi(v.y);
    }
    f32x4 r = { a0, a1, a2, a3 };
    *(f32x4*)(out + (size_t)i * 4) = r;
}

extern "C" void kernel_launch(void* const* d_in, const int* in_sizes, int n_in,
                              void* d_out, int out_size, void* d_ws, size_t ws_size,
                              hipStream_t stream) {
    const float* X = (const float*)d_in[0];
    const float* W = (const float*)d_in[1];
    float* out = (float*)d_out;
    const size_t need = (size_t)N_SPLIT * BATCH * OUT_DIM * 2;   // bf16 planes
    dim3 grid(NM, N_SPLIT);
    if (ws_size >= need) {
        kan_main<<<grid, 512, 0, stream>>>(X, W, d_ws, 0);
        kan_reduce<<<(BATCH * OUT_DIM / 4) / 256, 256, 0, stream>>>((const u32*)d_ws, out);
    } else {
        (void)hipMemsetAsync(d_out, 0, (size_t)out_size * sizeof(float), stream);
        kan_main<<<grid, 512, 0, stream>>>(X, W, d_out, 1);
    }
}

// Round 9
// 54.958 us; speedup vs baseline: 3.1516x; 3.1516x over previous
//
#include <hip/hip_runtime.h>
#include <stdint.h>

// Problem constants (from reference)
#define BATCH   8192
#define IN_DIM  256
#define OUT_DIM 64
#define NROW    68      // 67 spline rows + 1 silu row per d
#define N_SPLIT 16      // d-splits
#define D_SLICE 16      // d's per block (256/N_SPLIT)
#define N_STAGE 16      // 1 d per stage, double-buffered
#define M_BLK   256     // batch rows per block
#define NM      32      // 8192/M_BLK  (staging total ~ NM: keep at 32, R7 lesson)

typedef unsigned int u32;
typedef float f32x4 __attribute__((ext_vector_type(4)));
typedef u32   u32x2 __attribute__((ext_vector_type(2)));
typedef __bf16 bf16x2 __attribute__((ext_vector_type(2)));

#if defined(__has_builtin)
#  if __has_builtin(__builtin_amdgcn_fdot2_f32_bf16)
#    define HAVE_DOT2 1
#  endif
#endif
#ifndef HAVE_DOT2
#  define HAVE_DOT2 0
#endif

__device__ __forceinline__ u32 f2bf(float f) {              // f32 -> bf16 (RNE)
    u32 u = __float_as_uint(f);
    u += 0x7FFFu + ((u >> 16) & 1u);
    return u >> 16;
}
__device__ __forceinline__ float bflo(u32 u) { return __uint_as_float(u << 16); }
__device__ __forceinline__ float bfhi(u32 u) { return __uint_as_float(u & 0xFFFF0000u); }

// {lo, hi} f32 pair -> packed bf16x2 dword (HW v_cvt_pk_bf16_f32 via casts)
__device__ __forceinline__ u32 pkbf(float lo, float hi) {
    bf16x2 v = { (__bf16)lo, (__bf16)hi };
    u32 u;
    __builtin_memcpy(&u, &v, 4);
    return u;
}

// a, b are bf16x2 packed in u32 (element0 = low 16 bits): a0*b0 + a1*b1 + c
__device__ __forceinline__ float dot2bf(u32 a, u32 b, float c) {
#if HAVE_DOT2
    bf16x2 av, bv;
    __builtin_memcpy(&av, &a, 4);
    __builtin_memcpy(&bv, &b, 4);
    return __builtin_amdgcn_fdot2_f32_bf16(av, bv, c, false);
#else
    return fmaf(bflo(a), bflo(b), fmaf(bfhi(a), bfhi(b), c));
#endif
}

// knot t[i], i in [0,70]: 3 clamped zeros, linspace(0,1,65), 3 clamped ones.
__device__ __forceinline__ float knotf(int i) {
    return fminf(1.f, fmaxf(0.f, (float)(i - 3) * 0.015625f));
}

// Windowed Cox-de Boor (degree 3). Record: {c0|c1, c2|c3 (bf16x2), silu f32, s}
__device__ __forceinline__ void make_record(float x, u32 rec[4]) {
    int s = (int)floorf(x * 64.f);
    s = max(0, min(63, s));
    const int m = s + 3;
    float N0 = 1.f, N1, N2, N3;
    const float l1 = x - knotf(m);
    const float r1 = knotf(m + 1) - x;
    {
        float tmp = N0 / (r1 + l1);
        N0 = r1 * tmp;
        N1 = l1 * tmp;
    }
    const float l2 = x - knotf(m - 1);
    const float r2 = knotf(m + 2) - x;
    {
        float tmp = N0 / (r1 + l2);
        N0 = r1 * tmp;
        float saved = l2 * tmp;
        tmp = N1 / (r2 + l1);
        N1 = saved + r2 * tmp;
        N2 = l1 * tmp;
    }
    const float l3 = x - knotf(m - 2);
    const float r3 = knotf(m + 3) - x;
    {
        float tmp = N0 / (r1 + l3);
        N0 = r1 * tmp;
        float saved = l3 * tmp;
        tmp = N1 / (r2 + l2);
        N1 = saved + r2 * tmp;
        saved = l2 * tmp;
        tmp = N2 / (r3 + l1);
        N2 = saved + r3 * tmp;
        N3 = l1 * tmp;
    }
    const float silu = x / (1.f + __expf(-x));
    rec[0] = f2bf(N0) | (f2bf(N1) << 16);
    rec[1] = f2bf(N2) | (f2bf(N3) << 16);
    rec[2] = __float_as_uint(silu);
    rec[3] = (u32)s;
}

// LDS: two stage-buffers (double-buffered, 1 d each), 21248 B per buffer:
//   [0, 16896):        pair table: 66 pair-rows x 64 bf16x2, row stride 256 B,
//                      LINEAR (octet gather = one contiguous 128-B stripe)
//   [16896, 17152):    silu row (w row 67) as f32[64]
//   [17152, 21248):    coeff records [256 r] x 16 B
// Total 42496 B (same as R6).
#define TAB_OFF    0
#define SILU_OFF   16896
#define REC_OFF    17152
#define BUF_STRIDE 21248
#define LDS_U4     2656

// EMPIRICAL launch_bounds semantics on this ROCm (R1/R3/R5-R8 calibration):
// 2nd arg acts as min BLOCKS/CU (CUDA-style). For 512-thread (8-wave) blocks:
// arg=N -> 8N waves/CU -> 2N waves/SIMD -> VGPR cap = 512/(2N).
// arg=4 -> cap 64 (spill disaster, R1+R8). arg=2 -> cap 128 (demand ~100). 
__global__ __launch_bounds__(512, 2)
void kan_main(const float* __restrict__ X, const float* __restrict__ W,
              void* __restrict__ outbuf, int useAtomic) {
    __shared__ uint4 smem4[LDS_U4];
    char* sm = (char*)smem4;

    const int mb  = blockIdx.x;          // 0..31
    const int sp  = blockIdx.y;          // 0..15
    const int tid = threadIdx.x;
    const int r0  = mb * M_BLK;
    const int d0  = sp * D_SLICE;

    const int lane = tid & 63;
    const int wv   = tid >> 6;           // wave 0..7
    const int sub  = lane & 7;           // output-chunk selector
    const int g    = lane >> 3;          // row-in-round 0..7
    const int rb   = wv * 32;            // wave's local row base

    // staging entry decomposition (1056 entries = 512 + 512 + 32 tail)
    const int c16 = tid & 15;            // 16-B chunk in pair-row
    const int e0r = tid >> 4;            //  0..31
    const int e1r = e0r + 32;            // 32..63
    const int e2r = e0r + 64;            // 64..65 (tid < 32 only)

    // prefetch registers (T14 issue-early / write-late)
    float4 va0, vb0, va1, vb1, va2, vb2;
    float xreg = 0.f, sreg = 0.f;

#define LOAD_REGS(DS) do {                                                     \
        const float* wb_ = W + (size_t)(DS) * (NROW * OUT_DIM);                \
        const float* p0_ = wb_ + e0r * OUT_DIM + c16 * 4;                      \
        va0 = *(const float4*)p0_;  vb0 = *(const float4*)(p0_ + OUT_DIM);     \
        const float* p1_ = wb_ + e1r * OUT_DIM + c16 * 4;                      \
        va1 = *(const float4*)p1_;  vb1 = *(const float4*)(p1_ + OUT_DIM);     \
        if (tid < 32) {                                                        \
            const float* p2_ = wb_ + e2r * OUT_DIM + c16 * 4;                  \
            va2 = *(const float4*)p2_;  vb2 = *(const float4*)(p2_ + OUT_DIM); \
        }                                                                      \
        if (tid >= 448) sreg = wb_[67 * OUT_DIM + (tid - 448)];                \
        if (tid < 256)  xreg = X[(size_t)(r0 + tid) * IN_DIM + (DS)];          \
    } while (0)

#define WRITE_STAGE(BN) do {                                                   \
        char* b_ = (BN);                                                       \
        *(uint4*)(b_ + TAB_OFF + e0r * 256 + c16 * 16) =                       \
            make_uint4(pkbf(va0.x, vb0.x), pkbf(va0.y, vb0.y),                 \
                       pkbf(va0.z, vb0.z), pkbf(va0.w, vb0.w));                \
        *(uint4*)(b_ + TAB_OFF + e1r * 256 + c16 * 16) =                       \
            make_uint4(pkbf(va1.x, vb1.x), pkbf(va1.y, vb1.y),                 \
                       pkbf(va1.z, vb1.z), pkbf(va1.w, vb1.w));                \
        if (tid < 32)                                                          \
            *(uint4*)(b_ + TAB_OFF + e2r * 256 + c16 * 16) =                   \
                make_uint4(pkbf(va2.x, vb2.x), pkbf(va2.y, vb2.y),             \
                           pkbf(va2.z, vb2.z), pkbf(va2.w, vb2.w));            \
        if (tid >= 448) *(float*)(b_ + SILU_OFF + (tid - 448) * 4) = sreg;     \
        if (tid < 256) {                                                       \
            u32 rec_[4];                                                       \
            make_record(xreg, rec_);                                           \
            *(uint4*)(b_ + REC_OFF + (tid << 4)) =                             \
                make_uint4(rec_[0], rec_[1], rec_[2], rec_[3]);                \
        }                                                                      \
    } while (0)

    float acc[4][8];
#pragma unroll
    for (int t = 0; t < 4; ++t)
#pragma unroll
        for (int k = 0; k < 8; ++k) acc[t][k] = 0.f;

    // ---- prologue: fill buffer 0, prefetch stage 1 ----
    LOAD_REGS(d0);
    WRITE_STAGE(sm);
    __syncthreads();
    LOAD_REGS(d0 + 1);

    for (int st = 0; st < N_STAGE; ++st) {
        char* bc = sm + (st & 1) * BUF_STRIDE;
        char* bn = sm + ((st & 1) ^ 1) * BUF_STRIDE;

        // ---- compute from bc (gather + dot2, 32 rows/wave) ----
        const f32x4 w67a = *(const f32x4*)(bc + SILU_OFF + sub * 16);
        const f32x4 w67b = *(const f32x4*)(bc + SILU_OFF + 128 + sub * 16);
#pragma unroll
        for (int t = 0; t < 4; ++t) {
            const uint4 rec = *(const uint4*)(bc + REC_OFF + ((rb + t * 8 + g) << 4));
            const u32 c01 = rec.x, c23 = rec.y;
            const float silu = __uint_as_float(rec.z);
            const int s = (int)rec.w;
            const char* r1 = bc + TAB_OFF + s * 256 + sub * 16;        // pair-row s
            const char* r2 = bc + TAB_OFF + (s + 2) * 256 + sub * 16;  // pair-row s+2
            const uint4 p1  = *(const uint4*)(r1);          // outputs sub*4..+3
            const uint4 p1b = *(const uint4*)(r1 + 128);    // outputs 32+sub*4..+3
            const uint4 p2  = *(const uint4*)(r2);
            const uint4 p2b = *(const uint4*)(r2 + 128);
            acc[t][0] = dot2bf(c23, p2.x,  dot2bf(c01, p1.x,  acc[t][0]));
            acc[t][1] = dot2bf(c23, p2.y,  dot2bf(c01, p1.y,  acc[t][1]));
            acc[t][2] = dot2bf(c23, p2.z,  dot2bf(c01, p1.z,  acc[t][2]));
            acc[t][3] = dot2bf(c23, p2.w,  dot2bf(c01, p1.w,  acc[t][3]));
            acc[t][4] = dot2bf(c23, p2b.x, dot2bf(c01, p1b.x, acc[t][4]));
            acc[t][5] = dot2bf(c23, p2b.y, dot2bf(c01, p1b.y, acc[t][5]));
            acc[t][6] = dot2bf(c23, p2b.z, dot2bf(c01, p1b.z, acc[t][6]));
            acc[t][7] = dot2bf(c23, p2b.w, dot2bf(c01, p1b.w, acc[t][7]));
            acc[t][0] = fmaf(silu, w67a.x, acc[t][0]);
            acc[t][1] = fmaf(silu, w67a.y, acc[t][1]);
            acc[t][2] = fmaf(silu, w67a.z, acc[t][2]);
            acc[t][3] = fmaf(silu, w67a.w, acc[t][3]);
            acc[t][4] = fmaf(silu, w67b.x, acc[t][4]);
            acc[t][5] = fmaf(silu, w67b.y, acc[t][5]);
            acc[t][6] = fmaf(silu, w67b.z, acc[t][6]);
            acc[t][7] = fmaf(silu, w67b.w, acc[t][7]);
        }

        // ---- write next stage (prefetched regs), single barrier, prefetch ----
        if (st < N_STAGE - 1) {
            WRITE_STAGE(bn);
            __syncthreads();
            if (st < N_STAGE - 2) LOAD_REGS(d0 + st + 2);
        }
    }

    // ---- emit partials as bf16 planes (streamed once, read once) ----
    if (!useAtomic) {
        char* wsp = (char*)outbuf + (size_t)sp * (BATCH * OUT_DIM * 2);
#pragma unroll
        for (int t = 0; t < 4; ++t) {
            const int R = r0 + rb + t * 8 + g;
            u32x2 lo = { pkbf(acc[t][0], acc[t][1]), pkbf(acc[t][2], acc[t][3]) };
            u32x2 hi = { pkbf(acc[t][4], acc[t][5]), pkbf(acc[t][6], acc[t][7]) };
            __builtin_nontemporal_store(lo, (u32x2*)(wsp + (size_t)R * 128 + sub * 8));
            __builtin_nontemporal_store(hi, (u32x2*)(wsp + (size_t)R * 128 + 64 + sub * 8));
        }
    } else {
        float* out = (float*)outbuf;
#pragma unroll
        for (int t = 0; t < 4; ++t) {
            const int R = r0 + rb + t * 8 + g;
#pragma unroll
            for (int k = 0; k < 4; ++k) {
                atomicAdd(out + (size_t)R * 64 + sub * 4 + k, acc[t][k]);
                atomicAdd(out + (size_t)R * 64 + 32 + sub * 4 + k, acc[t][k + 4]);
            }
        }
    }
#undef LOAD_REGS
#undef WRITE_STAGE
}

__global__ __launch_bounds__(256)
void kan_reduce(const u32* __restrict__ ws, float* __restrict__ out) {
    const int i = blockIdx.x * 256 + threadIdx.x;   // u32x2 index (4 bf16), 131072
    const u32x2* w2 = (const u32x2*)ws;
    float a0 = 0.f, a1 = 0.f, a2 = 0.f, a3 = 0.f;
#pragma unroll
    for (int s = 0; s < N_SPLIT; ++s) {
        u32x2 v = __builtin_nontemporal_load(
            &w2[(size_t)s * (BATCH * OUT_DIM / 4) + i]);
        a0 += bflo(v.x); a1 += bfhi(v.x);
        a2 += bflo(v.y); a3 += bfhi(v.y);
    }
    f32x4 r = { a0, a1, a2, a3 };
    *(f32x4*)(out + (size_t)i * 4) = r;
}

extern "C" void kernel_launch(void* const* d_in, const int* in_sizes, int n_in,
                              void* d_out, int out_size, void* d_ws, size_t ws_size,
                              hipStream_t stream) {
    const float* X = (const float*)d_in[0];
    const float* W = (const float*)d_in[1];
    float* out = (float*)d_out;
    const size_t need = (size_t)N_SPLIT * BATCH * OUT_DIM * 2;   // bf16 planes
    dim3 grid(NM, N_SPLIT);
    if (ws_size >= need) {
        kan_main<<<grid, 512, 0, stream>>>(X, W, d_ws, 0);
        kan_reduce<<<(BATCH * OUT_DIM / 4) / 256, 256, 0, stream>>>((const u32*)d_ws, out);
    } else {
        (void)hipMemsetAsync(d_out, 0, (size_t)out_size * sizeof(float), stream);
        kan_main<<<grid, 512, 0, stream>>>(X, W, d_out, 1);
    }
}